// Round 4
// baseline (332.123 us; speedup 1.0000x reference)
//
#include <hip/hip_runtime.h>

#define HWSZ 4096
#define NTRI 136
#define NSTAT 152
#define NINST 512
#define GCNT 16
#define EPSW 1e-5f

typedef float v2f __attribute__((ext_vector_type(2)));
typedef float v4f __attribute__((ext_vector_type(4)));

// ---------------------------------------------------------------------------
// K1: per-instance stats, TRIANGLE-SPLIT across 2 blocks per instance,
// v4f (dwordx4) loads.
//   block 2b+0 (half A): s1[16] + cov rows c=0..3   (tri 0..57)  -> out [0..73]
//   block 2b+1 (half B): cov rows c=4..15           (tri 58..135)-> out [74..151]
//
// HISTORY (do not regress):
//  - (256,2) fused 152-accum: 87 us, latency-bound (VALUBusy 15%, 1.47 TB/s).
//  - (256,4) split: 128-reg cap -> spill (WRITE_SIZE 87 MB, 100 us).
//  - (256,3) split v2f: 87 us, NO spill, 2.57 TB/s logical. Occupancy gain
//    cancelled by 1.75x traffic. VGPR=76 reported, ~110 live.
//  - pair-cooperative shfl_xor variant: transient live set (v+w+lo+hi = 56
//    regs) + 76 accums -> demoted to scratch (WRITE 27 MB, 106 us). ABANDONED.
//  - [THIS] v2f -> v4f: tests "per-request overhead limits BW" (m13's 6.3TB/s
//    ceiling was measured with 16B loads; we issue 8B). Halves request count.
//  Spill tripwire: WRITE_SIZE must stay ~320 KB. Null tripwire: dur stuck at
//  87 us -> limiter is latency, go to explicit prefetch pipeline next.
//
// CRITICAL register discipline:
//  - position loop = "#pragma unroll 1"; EVERY loop indexing accumulators =
//    full unroll (dynamic indexing demotes the array to scratch).
// ---------------------------------------------------------------------------
__global__ __launch_bounds__(256, 3) void k_inst_stats(const float* __restrict__ x,
                                                       float* __restrict__ inst_stats) {
  const int bb = blockIdx.x;
  const int b = bb >> 1;      // instance
  const int half = bb & 1;    // triangle half (block-uniform branch)
  const int t = threadIdx.x;
  const int lane = t & 63;
  const int wv = t >> 6;
  const v4f* xb = (const v4f*)x + (size_t)b * 16 * 1024;  // 1024 v4f per channel row

  __shared__ float red[4 * 78];

  if (half == 0) {
    // ---- half A: s1 + triangle rows c=0..3 (58 pairs) ----
    float s1[16];
    float s2[58];
#pragma unroll
    for (int i = 0; i < 16; ++i) s1[i] = 0.f;
#pragma unroll
    for (int i = 0; i < 58; ++i) s2[i] = 0.f;

#pragma unroll 1
    for (int k = 0; k < 4; ++k) {
      const int f = t + k * 256;  // v4f index within a 1024-v4f channel row
      v4f v[16];
#pragma unroll
      for (int d = 0; d < 16; ++d) v[d] = xb[d * 1024 + f];
#pragma unroll
      for (int c = 0; c < 16; ++c) s1[c] += (v[c].x + v[c].y) + (v[c].z + v[c].w);
      int tri = 0;
#pragma unroll
      for (int c = 0; c < 4; ++c) {
#pragma unroll
        for (int d = c; d < 16; ++d) {
          s2[tri] += (v[c].x * v[d].x + v[c].y * v[d].y) +
                     (v[c].z * v[d].z + v[c].w * v[d].w);
          ++tri;
        }
      }
    }

    // wave shuffle reduce (fully unrolled), then cross-wave via LDS
#pragma unroll
    for (int q = 0; q < 16; ++q) {
      float v = s1[q];
#pragma unroll
      for (int off = 32; off > 0; off >>= 1) v += __shfl_down(v, off);
      if (lane == 0) red[wv * 78 + q] = v;
    }
#pragma unroll
    for (int q = 0; q < 58; ++q) {
      float v = s2[q];
#pragma unroll
      for (int off = 32; off > 0; off >>= 1) v += __shfl_down(v, off);
      if (lane == 0) red[wv * 78 + 16 + q] = v;
    }
    __syncthreads();
    if (t < 74) {
      inst_stats[(size_t)b * NSTAT + t] =
          red[t] + red[78 + t] + red[156 + t] + red[234 + t];
    }
  } else {
    // ---- half B: triangle rows c=4..15 (78 pairs), channels 4..15 only ----
    float s2[78];
#pragma unroll
    for (int i = 0; i < 78; ++i) s2[i] = 0.f;

#pragma unroll 1
    for (int k = 0; k < 4; ++k) {
      const int f = t + k * 256;
      v4f v[12];
#pragma unroll
      for (int d = 0; d < 12; ++d) v[d] = xb[(d + 4) * 1024 + f];
      int tri = 0;
#pragma unroll
      for (int c = 0; c < 12; ++c) {
#pragma unroll
        for (int d = c; d < 12; ++d) {
          s2[tri] += (v[c].x * v[d].x + v[c].y * v[d].y) +
                     (v[c].z * v[d].z + v[c].w * v[d].w);
          ++tri;
        }
      }
    }

#pragma unroll
    for (int q = 0; q < 78; ++q) {
      float v = s2[q];
#pragma unroll
      for (int off = 32; off > 0; off >>= 1) v += __shfl_down(v, off);
      if (lane == 0) red[wv * 78 + q] = v;
    }
    __syncthreads();
    if (t < 78) {
      inst_stats[(size_t)b * NSTAT + 74 + t] =
          red[t] + red[78 + t] + red[156 + t] + red[234 + t];
    }
  }
}

// ---------------------------------------------------------------------------
// K3: per-instance mixing + Newton-Schulz, with K2 (group stats) FUSED in:
// each block recomputes its group's 152 sums from inst_stats into LDS
// (311 KB buffer is L2-resident; 152 threads x 32 independent loads).
// One block (256 thr) per instance; thread t owns element (row=t>>4, col=t&15).
// Outputs folded affine transform: y = W' x + o.
// ---------------------------------------------------------------------------
__global__ __launch_bounds__(256) void k_newton(const float* __restrict__ inst_stats,
                                                const float* __restrict__ swm,
                                                const float* __restrict__ swv,
                                                const float* __restrict__ weight,
                                                const float* __restrict__ bias,
                                                float* __restrict__ apply_wm,
                                                float* __restrict__ apply_ofs) {
  const int b = blockIdx.x;
  const int g = b & 15;
  const int t = threadIdx.x;
  const int r = t >> 4;
  const int c = t & 15;

  __shared__ float P[256], Qm[256], Rm[256], CN[256], Wl[256];
  __shared__ float Mm[16], Mi[16], Mb[16];
  __shared__ float Gs[NSTAT];

  // fused K2: group sums over the 32 instances of this group
  if (t < NSTAT) {
    float s = 0.f;
#pragma unroll 8
    for (int n = 0; n < 32; ++n) s += inst_stats[(size_t)(n * GCNT + g) * NSTAT + t];
    Gs[t] = s;
  }

  float a0 = swm[0], a1 = swm[1];
  float mx = fmaxf(a0, a1);
  float e0 = expf(a0 - mx), e1 = expf(a1 - mx);
  const float mw0 = e0 / (e0 + e1), mw1 = e1 / (e0 + e1);
  a0 = swv[0]; a1 = swv[1];
  mx = fmaxf(a0, a1);
  e0 = expf(a0 - mx); e1 = expf(a1 - mx);
  const float vw0 = e0 / (e0 + e1), vw1 = e1 / (e0 + e1);

  const float inv_hw = 1.0f / (float)HWSZ;
  const float inv_nhw = 1.0f / (32.0f * (float)HWSZ);

  __syncthreads();

  if (t < 16) {
    const float mi = inst_stats[(size_t)b * NSTAT + t] * inv_hw;
    const float mb = Gs[t] * inv_nhw;
    Mi[t] = mi;
    Mb[t] = mb;
    Mm[t] = mw0 * mb + mw1 * mi;
  }
  __syncthreads();

  const int cmin = (r < c) ? r : c;
  const int cmax = (r < c) ? c : r;
  const int tri = 15 * cmin - (cmin * (cmin - 1)) / 2 + cmax + 16;
  const float cin = inst_stats[(size_t)b * NSTAT + tri] * inv_hw - Mi[r] * Mi[c];
  const float cbn = Gs[tri] * inv_nhw - Mb[r] * Mb[c];
  float cov = vw0 * cbn + vw1 * cin + ((r == c) ? EPSW : 0.0f);

  Qm[t] = cov;
  __syncthreads();
  float trace = 0.f;
#pragma unroll
  for (int i = 0; i < 16; ++i) trace += Qm[i * 16 + i];
  const float rTr = 1.0f / trace;

  CN[t] = cov * rTr;
  P[t] = (r == c) ? 1.0f : 0.0f;
  __syncthreads();

  for (int it = 0; it < 5; ++it) {
    float q = 0.f;
#pragma unroll
    for (int k = 0; k < 16; ++k) q += P[r * 16 + k] * P[k * 16 + c];
    Qm[t] = q;
    __syncthreads();
    float rr = 0.f;
#pragma unroll
    for (int k = 0; k < 16; ++k) rr += Qm[r * 16 + k] * P[k * 16 + c];
    Rm[t] = rr;
    __syncthreads();
    float tt = 0.f;
#pragma unroll
    for (int k = 0; k < 16; ++k) tt += Rm[r * 16 + k] * CN[k * 16 + c];
    const float np = 1.5f * P[t] - 0.5f * tt;
    __syncthreads();
    P[t] = np;
    __syncthreads();
  }

  const float sr = sqrtf(rTr);
  const float wel = P[t] * sr * weight[g * 16 + r];
  Wl[t] = wel;
  apply_wm[(size_t)b * 256 + t] = wel;
  __syncthreads();
  if (t < 16) {
    float acc = 0.f;
#pragma unroll
    for (int d = 0; d < 16; ++d) acc += Wl[t * 16 + d] * Mm[d];
    apply_ofs[(size_t)b * 16 + t] = bias[g * 16 + t] - acc;
  }
}

// ---------------------------------------------------------------------------
// K4: apply y = W' x + o. 4 blocks per instance (2048 blocks); each thread
// owns ONE float4 column (all 16 channels). ~100 live VGPRs -> 4 waves/EU.
// ---------------------------------------------------------------------------
__global__ __launch_bounds__(256, 4) void k_apply(const float* __restrict__ x,
                                                  const float* __restrict__ apply_wm,
                                                  const float* __restrict__ apply_ofs,
                                                  float* __restrict__ y) {
  const int bb = blockIdx.x;
  const int b = bb >> 2;      // instance
  const int chunk = bb & 3;   // position chunk
  const int t = threadIdx.x;

  __shared__ float Wl[256];
  __shared__ float Ol[16];
  Wl[t] = apply_wm[(size_t)b * 256 + t];
  if (t < 16) Ol[t] = apply_ofs[(size_t)b * 16 + t];
  __syncthreads();

  const v4f* xb = (const v4f*)x + (size_t)b * 16 * 1024;  // 1024 v4f per channel row
  v4f* yb = (v4f*)y + (size_t)b * 16 * 1024;
  const int f = chunk * 256 + t;  // v4f index within channel row

  v4f v[16];
#pragma unroll
  for (int d = 0; d < 16; ++d) v[d] = xb[d * 1024 + f];

#pragma unroll
  for (int cch = 0; cch < 16; ++cch) {
    v4f acc = Ol[cch];
#pragma unroll
    for (int d = 0; d < 16; ++d) acc += Wl[cch * 16 + d] * v[d];
    yb[cch * 1024 + f] = acc;
  }
}

// ---------------------------------------------------------------------------
extern "C" void kernel_launch(void* const* d_in, const int* in_sizes, int n_in,
                              void* d_out, int out_size, void* d_ws, size_t ws_size,
                              hipStream_t stream) {
  const float* x = (const float*)d_in[0];
  const float* swm = (const float*)d_in[1];
  const float* swv = (const float*)d_in[2];
  const float* weight = (const float*)d_in[3];
  const float* bias = (const float*)d_in[4];
  float* out = (float*)d_out;

  float* ws = (float*)d_ws;
  float* inst = ws;                          // 512*152
  float* awm = inst + (size_t)NINST * NSTAT; // 512*256
  float* aofs = awm + (size_t)NINST * 256;   // 512*16

  k_inst_stats<<<NINST * 2, 256, 0, stream>>>(x, inst);
  k_newton<<<NINST, 256, 0, stream>>>(inst, swm, swv, weight, bias, awm, aofs);
  k_apply<<<NINST * 4, 256, 0, stream>>>(x, awm, aofs, out);
}

// Round 5
// 297.541 us; speedup vs baseline: 1.1162x; 1.1162x over previous
//
#include <hip/hip_runtime.h>
#include <stdint.h>

#define HWSZ 4096
#define NTRI 136
#define NSTAT 152
#define NINST 512
#define GCNT 16
#define EPSW 1e-5f
#define CHUNK 512  // positions per staged chunk (32 KB per chunk: 16ch x 512 x 4B)
#define NCHUNK 8

typedef float v2f __attribute__((ext_vector_type(2)));
typedef float v4f __attribute__((ext_vector_type(4)));

typedef __attribute__((address_space(3))) float lds_f;
typedef const __attribute__((address_space(1))) float glb_f;

// ---------------------------------------------------------------------------
// K1: per-instance stats, FUSED (152 accums) + double-buffered LDS staging via
// global_load_lds (zero VGPR load-destinations).
//
// WHY (history, do not regress):
//  - All register-level restructures of K1 hit the same wall: accumulators
//    (74-152) + in-flight load dests exceed the reg cap -> compiler either
//    spills (rounds 1/3/4: WRITE_SIZE 27-122 MB) or serializes loads to ~2
//    in flight/wave (rounds 0/2: 87 us, VALUBusy 15%, 0.8-1.3 TB/s HBM =
//    4.3x above the 20 us memory floor).
//  - global_load_lds breaks the deadlock: staging consumes NO dest VGPRs, so
//    a whole 32 KB chunk is in flight at once while accums stay in registers.
//  - (256,2): 256-reg cap, round 0 proved 152 accums + 32 transient fit here.
//    LDS 68 KB/block -> exactly 2 blocks/CU, grid 512 = 2/CU, no tail.
//  Spill tripwire: WRITE_SIZE must stay ~320 KB.
//  Null tripwire: dur >= 60 us with clean WRITE -> serialization theory wrong.
//
// CRITICAL register discipline:
//  - chunk loop = "#pragma unroll 1"; EVERY loop indexing s1/s2 = full unroll
//    (dynamic indexing demotes the array to scratch).
// ---------------------------------------------------------------------------
__device__ __forceinline__ void stage_chunk(const float* __restrict__ xb,
                                            float* bufp, int wv, int lane, int ck) {
  // 32 issues of 1 KB (64 lanes x 16 B); wave wv does channels 4wv..4wv+3.
  // HW semantics (m104/m108): LDS dest = wave-uniform base + lane*16;
  // global source address is per-lane.
#pragma unroll
  for (int ii = 0; ii < 8; ++ii) {
    const int d = wv * 4 + (ii >> 1);
    const int q = ii & 1;
    __builtin_amdgcn_global_load_lds(
        (glb_f*)(xb + (size_t)d * HWSZ + (size_t)ck * CHUNK + q * 256 + lane * 4),
        (lds_f*)(bufp + d * CHUNK + q * 256), 16, 0, 0);
  }
}

__global__ __launch_bounds__(256, 2) void k_inst_stats(const float* __restrict__ x,
                                                       float* __restrict__ inst_stats) {
  const int b = blockIdx.x;
  const int t = threadIdx.x;
  const int lane = t & 63;
  const int wv = t >> 6;

  __shared__ float buf[2][16 * CHUNK];  // 2 x 32 KB
  __shared__ float red[4 * NSTAT];

  const float* xb = x + (size_t)b * 16 * HWSZ;

  float s1[16];
  float s2[NTRI];
#pragma unroll
  for (int i = 0; i < 16; ++i) s1[i] = 0.f;
#pragma unroll
  for (int i = 0; i < NTRI; ++i) s2[i] = 0.f;

  stage_chunk(xb, &buf[0][0], wv, lane, 0);
  __syncthreads();  // drains vmcnt(0): chunk 0 resident

#pragma unroll 1
  for (int ck = 0; ck < NCHUNK; ++ck) {
    if (ck + 1 < NCHUNK) stage_chunk(xb, &buf[(ck + 1) & 1][0], wv, lane, ck + 1);
    const float* bc = &buf[ck & 1][0];
    // thread t owns position pair 2t..2t+1 of this chunk.
    // bank check: lane stride 8 B -> 2 lanes/bank = free (m136).
    v2f v[16];
#pragma unroll
    for (int d = 0; d < 16; ++d) v[d] = *(const v2f*)&bc[d * CHUNK + 2 * t];
#pragma unroll
    for (int c = 0; c < 16; ++c) s1[c] += v[c].x + v[c].y;
    int tri = 0;
#pragma unroll
    for (int c = 0; c < 16; ++c) {
#pragma unroll
      for (int d = c; d < 16; ++d) {
        s2[tri] += v[c].x * v[d].x + v[c].y * v[d].y;
        ++tri;
      }
    }
    // barrier: (a) waits next chunk's loads (vmcnt drain), (b) protects the
    // buffer we overwrite next iteration from in-progress readers.
    __syncthreads();
  }

  // block reduction: wave shuffle (FULLY UNROLLED - static s1/s2 indexing),
  // then cross-wave via LDS.
#pragma unroll
  for (int q = 0; q < 16; ++q) {
    float v = s1[q];
#pragma unroll
    for (int off = 32; off > 0; off >>= 1) v += __shfl_down(v, off);
    if (lane == 0) red[wv * NSTAT + q] = v;
  }
#pragma unroll
  for (int q = 0; q < NTRI; ++q) {
    float v = s2[q];
#pragma unroll
    for (int off = 32; off > 0; off >>= 1) v += __shfl_down(v, off);
    if (lane == 0) red[wv * NSTAT + 16 + q] = v;
  }
  __syncthreads();
  if (t < NSTAT) {
    inst_stats[(size_t)b * NSTAT + t] =
        red[t] + red[NSTAT + t] + red[2 * NSTAT + t] + red[3 * NSTAT + t];
  }
}

// ---------------------------------------------------------------------------
// K3: per-instance mixing + Newton-Schulz, with K2 (group stats) FUSED in:
// each block recomputes its group's 152 sums from inst_stats into LDS
// (311 KB buffer is L2-resident; 152 threads x 32 independent loads).
// One block (256 thr) per instance; thread t owns element (row=t>>4, col=t&15).
// Outputs folded affine transform: y = W' x + o.
// ---------------------------------------------------------------------------
__global__ __launch_bounds__(256) void k_newton(const float* __restrict__ inst_stats,
                                                const float* __restrict__ swm,
                                                const float* __restrict__ swv,
                                                const float* __restrict__ weight,
                                                const float* __restrict__ bias,
                                                float* __restrict__ apply_wm,
                                                float* __restrict__ apply_ofs) {
  const int b = blockIdx.x;
  const int g = b & 15;
  const int t = threadIdx.x;
  const int r = t >> 4;
  const int c = t & 15;

  __shared__ float P[256], Qm[256], Rm[256], CN[256], Wl[256];
  __shared__ float Mm[16], Mi[16], Mb[16];
  __shared__ float Gs[NSTAT];

  // fused K2: group sums over the 32 instances of this group
  if (t < NSTAT) {
    float s = 0.f;
#pragma unroll 8
    for (int n = 0; n < 32; ++n) s += inst_stats[(size_t)(n * GCNT + g) * NSTAT + t];
    Gs[t] = s;
  }

  float a0 = swm[0], a1 = swm[1];
  float mx = fmaxf(a0, a1);
  float e0 = expf(a0 - mx), e1 = expf(a1 - mx);
  const float mw0 = e0 / (e0 + e1), mw1 = e1 / (e0 + e1);
  a0 = swv[0]; a1 = swv[1];
  mx = fmaxf(a0, a1);
  e0 = expf(a0 - mx); e1 = expf(a1 - mx);
  const float vw0 = e0 / (e0 + e1), vw1 = e1 / (e0 + e1);

  const float inv_hw = 1.0f / (float)HWSZ;
  const float inv_nhw = 1.0f / (32.0f * (float)HWSZ);

  __syncthreads();

  if (t < 16) {
    const float mi = inst_stats[(size_t)b * NSTAT + t] * inv_hw;
    const float mb = Gs[t] * inv_nhw;
    Mi[t] = mi;
    Mb[t] = mb;
    Mm[t] = mw0 * mb + mw1 * mi;
  }
  __syncthreads();

  const int cmin = (r < c) ? r : c;
  const int cmax = (r < c) ? c : r;
  const int tri = 15 * cmin - (cmin * (cmin - 1)) / 2 + cmax + 16;
  const float cin = inst_stats[(size_t)b * NSTAT + tri] * inv_hw - Mi[r] * Mi[c];
  const float cbn = Gs[tri] * inv_nhw - Mb[r] * Mb[c];
  float cov = vw0 * cbn + vw1 * cin + ((r == c) ? EPSW : 0.0f);

  Qm[t] = cov;
  __syncthreads();
  float trace = 0.f;
#pragma unroll
  for (int i = 0; i < 16; ++i) trace += Qm[i * 16 + i];
  const float rTr = 1.0f / trace;

  CN[t] = cov * rTr;
  P[t] = (r == c) ? 1.0f : 0.0f;
  __syncthreads();

  for (int it = 0; it < 5; ++it) {
    float q = 0.f;
#pragma unroll
    for (int k = 0; k < 16; ++k) q += P[r * 16 + k] * P[k * 16 + c];
    Qm[t] = q;
    __syncthreads();
    float rr = 0.f;
#pragma unroll
    for (int k = 0; k < 16; ++k) rr += Qm[r * 16 + k] * P[k * 16 + c];
    Rm[t] = rr;
    __syncthreads();
    float tt = 0.f;
#pragma unroll
    for (int k = 0; k < 16; ++k) tt += Rm[r * 16 + k] * CN[k * 16 + c];
    const float np = 1.5f * P[t] - 0.5f * tt;
    __syncthreads();
    P[t] = np;
    __syncthreads();
  }

  const float sr = sqrtf(rTr);
  const float wel = P[t] * sr * weight[g * 16 + r];
  Wl[t] = wel;
  apply_wm[(size_t)b * 256 + t] = wel;
  __syncthreads();
  if (t < 16) {
    float acc = 0.f;
#pragma unroll
    for (int d = 0; d < 16; ++d) acc += Wl[t * 16 + d] * Mm[d];
    apply_ofs[(size_t)b * 16 + t] = bias[g * 16 + t] - acc;
  }
}

// ---------------------------------------------------------------------------
// K4: apply y = W' x + o. 4 blocks per instance (2048 blocks); each thread
// owns ONE float4 column (all 16 channels). ~100 live VGPRs -> 4 waves/EU.
// ---------------------------------------------------------------------------
__global__ __launch_bounds__(256, 4) void k_apply(const float* __restrict__ x,
                                                  const float* __restrict__ apply_wm,
                                                  const float* __restrict__ apply_ofs,
                                                  float* __restrict__ y) {
  const int bb = blockIdx.x;
  const int b = bb >> 2;      // instance
  const int chunk = bb & 3;   // position chunk
  const int t = threadIdx.x;

  __shared__ float Wl[256];
  __shared__ float Ol[16];
  Wl[t] = apply_wm[(size_t)b * 256 + t];
  if (t < 16) Ol[t] = apply_ofs[(size_t)b * 16 + t];
  __syncthreads();

  const v4f* xb = (const v4f*)x + (size_t)b * 16 * 1024;  // 1024 v4f per channel row
  v4f* yb = (v4f*)y + (size_t)b * 16 * 1024;
  const int f = chunk * 256 + t;  // v4f index within channel row

  v4f v[16];
#pragma unroll
  for (int d = 0; d < 16; ++d) v[d] = xb[d * 1024 + f];

#pragma unroll
  for (int cch = 0; cch < 16; ++cch) {
    v4f acc = Ol[cch];
#pragma unroll
    for (int d = 0; d < 16; ++d) acc += Wl[cch * 16 + d] * v[d];
    yb[cch * 1024 + f] = acc;
  }
}

// ---------------------------------------------------------------------------
extern "C" void kernel_launch(void* const* d_in, const int* in_sizes, int n_in,
                              void* d_out, int out_size, void* d_ws, size_t ws_size,
                              hipStream_t stream) {
  const float* x = (const float*)d_in[0];
  const float* swm = (const float*)d_in[1];
  const float* swv = (const float*)d_in[2];
  const float* weight = (const float*)d_in[3];
  const float* bias = (const float*)d_in[4];
  float* out = (float*)d_out;

  float* ws = (float*)d_ws;
  float* inst = ws;                          // 512*152
  float* awm = inst + (size_t)NINST * NSTAT; // 512*256
  float* aofs = awm + (size_t)NINST * 256;   // 512*16

  k_inst_stats<<<NINST, 256, 0, stream>>>(x, inst);
  k_newton<<<NINST, 256, 0, stream>>>(inst, swm, swv, weight, bias, awm, aofs);
  k_apply<<<NINST * 4, 256, 0, stream>>>(x, awm, aofs, out);
}

// Round 6
// 275.988 us; speedup vs baseline: 1.2034x; 1.0781x over previous
//
#include <hip/hip_runtime.h>
#include <stdint.h>

#define HWSZ 4096
#define NTRI 136
#define NSTAT 152
#define NINST 512
#define GCNT 16
#define EPSW 1e-5f
#define CHUNK 512  // positions per staged chunk (32 KB: 16ch x 512 x 4B)
#define NCHUNK 8

typedef float v2f __attribute__((ext_vector_type(2)));
typedef float v4f __attribute__((ext_vector_type(4)));

typedef __attribute__((address_space(3))) float lds_f;
typedef const __attribute__((address_space(1))) float glb_f;

// ---------------------------------------------------------------------------
// K1: per-instance stats. ROW-PAIR WAVE SPLIT + DMA-staged LDS double buffer.
//
// Finding after 6 rounds: delivered read BW == ~0.73 B/cyc PER RESIDENT WAVE
// across every structure (reg loads / split / spilled / DMA-staged). The
// limiter is resident wave count, and per-thread ownership of all 152 stats
// (VGPR >= 124 -> 2-4 waves/SIMD) capped us at 8-12 waves/CU forever.
//
// Fix: wave w of 8 owns triangle rows {w, 15-w} = exactly 19 stats
// (2 s1 + (16-w) + (w+1) pairs -> uniform 19 for every w). Per-thread state:
// 19 accums + <=16 transient v4f ~ 95 VGPR -> 4 waves/SIMD. One 512-thread
// block per instance, x staged to LDS via global_load_lds (32 KB dbuf chunks),
// each wave reads its channels (w..15) from LDS. 2 blocks/CU resident ->
// 16 waves/CU = 2x round 5.
//
// Static-indexing discipline (scratch-demotion rule): wave role dispatched
// via template<int W> switch on wave-uniform wv; ALL accumulator loops have
// constexpr bounds and are fully unrolled. chunk loop stays "#pragma unroll 1".
// Spill tripwire: WRITE_SIZE ~304 KB. VGPR must stay <= 128.
//
// Stat->slot mapping (wave w):
//   slot 0       : s1[w]
//   slot 1       : s1[15-w]
//   slot 2..17-w : pair (w, w+s-2)        [row w]
//   slot 18-w..18: pair (15-w, s-3)       [row 15-w]
// ---------------------------------------------------------------------------
__device__ __forceinline__ void stage_chunk(const float* __restrict__ xb,
                                            float* bufp, int wv, int lane, int ck) {
  // wave wv stages channels 2wv, 2wv+1: 4 issues of 1 KB (64 lanes x 16 B).
  // LDS dest = wave-uniform base + lane*16 (m104/m108); global src per-lane.
#pragma unroll
  for (int ii = 0; ii < 4; ++ii) {
    const int ch = wv * 2 + (ii >> 1);
    const int q = ii & 1;
    __builtin_amdgcn_global_load_lds(
        (glb_f*)(xb + (size_t)ch * HWSZ + ck * CHUNK + q * 256 + lane * 4),
        (lds_f*)(bufp + ch * CHUNK + q * 256), 16, 0, 0);
  }
}

template <int W>
__device__ __forceinline__ void accum_chunk(const float* bc, int lane, float acc[19]) {
  constexpr int NCH = 16 - W;   // channels W..15 live in v[0..NCH-1]
  constexpr int J2 = 15 - 2 * W; // v-index of channel 15-W
#pragma unroll
  for (int pg = 0; pg < 2; ++pg) {
    v4f v[NCH];
#pragma unroll
    for (int j = 0; j < NCH; ++j)
      v[j] = *(const v4f*)&bc[(W + j) * CHUNK + pg * 256 + lane * 4];
    acc[0] += (v[0].x + v[0].y) + (v[0].z + v[0].w);
    acc[1] += (v[J2].x + v[J2].y) + (v[J2].z + v[J2].w);
#pragma unroll
    for (int s = 2; s <= 17 - W; ++s)
      acc[s] += v[0].x * v[s - 2].x + v[0].y * v[s - 2].y +
                v[0].z * v[s - 2].z + v[0].w * v[s - 2].w;
#pragma unroll
    for (int s = 18 - W; s <= 18; ++s)
      acc[s] += v[J2].x * v[s - 3 - W].x + v[J2].y * v[s - 3 - W].y +
                v[J2].z * v[s - 3 - W].z + v[J2].w * v[s - 3 - W].w;
  }
}

__global__ __launch_bounds__(512, 4) void k_inst_stats(const float* __restrict__ x,
                                                       float* __restrict__ inst_stats) {
  const int b = blockIdx.x;
  const int t = threadIdx.x;
  const int lane = t & 63;
  const int wv = t >> 6;  // 0..7: owns rows {wv, 15-wv}
  const float* xb = x + (size_t)b * 16 * HWSZ;

  __shared__ __align__(16) float buf[2][16 * CHUNK];  // 2 x 32 KB
  __shared__ float red[8 * 19];

  float acc[19];
#pragma unroll
  for (int i = 0; i < 19; ++i) acc[i] = 0.f;

  stage_chunk(xb, &buf[0][0], wv, lane, 0);
  __syncthreads();  // drains vmcnt(0): chunk 0 resident

#pragma unroll 1
  for (int ck = 0; ck < NCHUNK; ++ck) {
    if (ck + 1 < NCHUNK) stage_chunk(xb, &buf[(ck + 1) & 1][0], wv, lane, ck + 1);
    const float* bc = &buf[ck & 1][0];
    switch (wv) {  // wave-uniform dispatch -> static accumulator indexing
      case 0: accum_chunk<0>(bc, lane, acc); break;
      case 1: accum_chunk<1>(bc, lane, acc); break;
      case 2: accum_chunk<2>(bc, lane, acc); break;
      case 3: accum_chunk<3>(bc, lane, acc); break;
      case 4: accum_chunk<4>(bc, lane, acc); break;
      case 5: accum_chunk<5>(bc, lane, acc); break;
      case 6: accum_chunk<6>(bc, lane, acc); break;
      default: accum_chunk<7>(bc, lane, acc); break;
    }
    __syncthreads();  // waits next chunk's DMA + protects buffer reuse
  }

  // wave-internal reduce of the wave's 19 stats (static indexing)
#pragma unroll
  for (int q = 0; q < 19; ++q) {
    float v = acc[q];
#pragma unroll
    for (int off = 32; off > 0; off >>= 1) v += __shfl_down(v, off);
    if (lane == 0) red[wv * 19 + q] = v;
  }
  __syncthreads();
  if (t < 8 * 19) {  // t = w*19 + s
    const int w = t / 19;
    const int s = t - w * 19;
    int gidx;
    if (s == 0) {
      gidx = w;
    } else if (s == 1) {
      gidx = 15 - w;
    } else if (s <= 17 - w) {
      const int a = w, d = w + s - 2;
      gidx = 16 + 15 * a - (a * (a - 1)) / 2 + d;
    } else {
      const int a = 15 - w, d = s - 3;
      gidx = 16 + 15 * a - (a * (a - 1)) / 2 + d;
    }
    inst_stats[(size_t)b * NSTAT + gidx] = red[t];
  }
}

// ---------------------------------------------------------------------------
// K3: per-instance mixing + Newton-Schulz, with K2 (group stats) FUSED in:
// each block recomputes its group's 152 sums from inst_stats into LDS
// (311 KB buffer is L2-resident; 152 threads x 32 independent loads).
// One block (256 thr) per instance; thread t owns element (row=t>>4, col=t&15).
// Outputs folded affine transform: y = W' x + o.
// ---------------------------------------------------------------------------
__global__ __launch_bounds__(256) void k_newton(const float* __restrict__ inst_stats,
                                                const float* __restrict__ swm,
                                                const float* __restrict__ swv,
                                                const float* __restrict__ weight,
                                                const float* __restrict__ bias,
                                                float* __restrict__ apply_wm,
                                                float* __restrict__ apply_ofs) {
  const int b = blockIdx.x;
  const int g = b & 15;
  const int t = threadIdx.x;
  const int r = t >> 4;
  const int c = t & 15;

  __shared__ float P[256], Qm[256], Rm[256], CN[256], Wl[256];
  __shared__ float Mm[16], Mi[16], Mb[16];
  __shared__ float Gs[NSTAT];

  // fused K2: group sums over the 32 instances of this group
  if (t < NSTAT) {
    float s = 0.f;
#pragma unroll 8
    for (int n = 0; n < 32; ++n) s += inst_stats[(size_t)(n * GCNT + g) * NSTAT + t];
    Gs[t] = s;
  }

  float a0 = swm[0], a1 = swm[1];
  float mx = fmaxf(a0, a1);
  float e0 = expf(a0 - mx), e1 = expf(a1 - mx);
  const float mw0 = e0 / (e0 + e1), mw1 = e1 / (e0 + e1);
  a0 = swv[0]; a1 = swv[1];
  mx = fmaxf(a0, a1);
  e0 = expf(a0 - mx); e1 = expf(a1 - mx);
  const float vw0 = e0 / (e0 + e1), vw1 = e1 / (e0 + e1);

  const float inv_hw = 1.0f / (float)HWSZ;
  const float inv_nhw = 1.0f / (32.0f * (float)HWSZ);

  __syncthreads();

  if (t < 16) {
    const float mi = inst_stats[(size_t)b * NSTAT + t] * inv_hw;
    const float mb = Gs[t] * inv_nhw;
    Mi[t] = mi;
    Mb[t] = mb;
    Mm[t] = mw0 * mb + mw1 * mi;
  }
  __syncthreads();

  const int cmin = (r < c) ? r : c;
  const int cmax = (r < c) ? c : r;
  const int tri = 15 * cmin - (cmin * (cmin - 1)) / 2 + cmax + 16;
  const float cin = inst_stats[(size_t)b * NSTAT + tri] * inv_hw - Mi[r] * Mi[c];
  const float cbn = Gs[tri] * inv_nhw - Mb[r] * Mb[c];
  float cov = vw0 * cbn + vw1 * cin + ((r == c) ? EPSW : 0.0f);

  Qm[t] = cov;
  __syncthreads();
  float trace = 0.f;
#pragma unroll
  for (int i = 0; i < 16; ++i) trace += Qm[i * 16 + i];
  const float rTr = 1.0f / trace;

  CN[t] = cov * rTr;
  P[t] = (r == c) ? 1.0f : 0.0f;
  __syncthreads();

  for (int it = 0; it < 5; ++it) {
    float q = 0.f;
#pragma unroll
    for (int k = 0; k < 16; ++k) q += P[r * 16 + k] * P[k * 16 + c];
    Qm[t] = q;
    __syncthreads();
    float rr = 0.f;
#pragma unroll
    for (int k = 0; k < 16; ++k) rr += Qm[r * 16 + k] * P[k * 16 + c];
    Rm[t] = rr;
    __syncthreads();
    float tt = 0.f;
#pragma unroll
    for (int k = 0; k < 16; ++k) tt += Rm[r * 16 + k] * CN[k * 16 + c];
    const float np = 1.5f * P[t] - 0.5f * tt;
    __syncthreads();
    P[t] = np;
    __syncthreads();
  }

  const float sr = sqrtf(rTr);
  const float wel = P[t] * sr * weight[g * 16 + r];
  Wl[t] = wel;
  apply_wm[(size_t)b * 256 + t] = wel;
  __syncthreads();
  if (t < 16) {
    float acc = 0.f;
#pragma unroll
    for (int d = 0; d < 16; ++d) acc += Wl[t * 16 + d] * Mm[d];
    apply_ofs[(size_t)b * 16 + t] = bias[g * 16 + t] - acc;
  }
}

// ---------------------------------------------------------------------------
// K4: apply y = W' x + o. 4 blocks per instance (2048 blocks); each thread
// owns ONE float4 column (all 16 channels). ~100 live VGPRs -> 4 waves/EU.
// ---------------------------------------------------------------------------
__global__ __launch_bounds__(256, 4) void k_apply(const float* __restrict__ x,
                                                  const float* __restrict__ apply_wm,
                                                  const float* __restrict__ apply_ofs,
                                                  float* __restrict__ y) {
  const int bb = blockIdx.x;
  const int b = bb >> 2;      // instance
  const int chunk = bb & 3;   // position chunk
  const int t = threadIdx.x;

  __shared__ float Wl[256];
  __shared__ float Ol[16];
  Wl[t] = apply_wm[(size_t)b * 256 + t];
  if (t < 16) Ol[t] = apply_ofs[(size_t)b * 16 + t];
  __syncthreads();

  const v4f* xb = (const v4f*)x + (size_t)b * 16 * 1024;  // 1024 v4f per channel row
  v4f* yb = (v4f*)y + (size_t)b * 16 * 1024;
  const int f = chunk * 256 + t;  // v4f index within channel row

  v4f v[16];
#pragma unroll
  for (int d = 0; d < 16; ++d) v[d] = xb[d * 1024 + f];

#pragma unroll
  for (int cch = 0; cch < 16; ++cch) {
    v4f acc = Ol[cch];
#pragma unroll
    for (int d = 0; d < 16; ++d) acc += Wl[cch * 16 + d] * v[d];
    yb[cch * 1024 + f] = acc;
  }
}

// ---------------------------------------------------------------------------
extern "C" void kernel_launch(void* const* d_in, const int* in_sizes, int n_in,
                              void* d_out, int out_size, void* d_ws, size_t ws_size,
                              hipStream_t stream) {
  const float* x = (const float*)d_in[0];
  const float* swm = (const float*)d_in[1];
  const float* swv = (const float*)d_in[2];
  const float* weight = (const float*)d_in[3];
  const float* bias = (const float*)d_in[4];
  float* out = (float*)d_out;

  float* ws = (float*)d_ws;
  float* inst = ws;                          // 512*152
  float* awm = inst + (size_t)NINST * NSTAT; // 512*256
  float* aofs = awm + (size_t)NINST * 256;   // 512*16

  k_inst_stats<<<NINST, 512, 0, stream>>>(x, inst);
  k_newton<<<NINST, 256, 0, stream>>>(inst, swm, swv, weight, bias, awm, aofs);
  k_apply<<<NINST * 4, 256, 0, stream>>>(x, awm, aofs, out);
}